// Round 2
// 343.430 us; speedup vs baseline: 1.0165x; 1.0165x over previous
//
#include <hip/hip_runtime.h>
#include <math.h>

#define B_    8
#define N_TOK 3136
#define C_    384
#define DH    48
#define NK    784
#define HID   768
#define M1    25088
#define M2    6272
#define M1Q   6272      // quarter of M1

typedef unsigned short u16;
typedef __attribute__((ext_vector_type(8))) short bf16x8;
typedef __attribute__((ext_vector_type(4))) float f32x4;

__device__ __forceinline__ float b2f(u16 u) {
  return __uint_as_float(((unsigned)u) << 16);
}
__device__ __forceinline__ u16 f2b(float f) {
  unsigned u = __float_as_uint(f);
  return (u16)((u + 0x7fffu + ((u >> 16) & 1u)) >> 16);  // RNE
}
__device__ __forceinline__ u16 f2b_trunc(float f) {
  return (u16)(__float_as_uint(f) >> 16);
}
__device__ __forceinline__ void gload_lds16(const u16* g, u16* l) {
  __builtin_amdgcn_global_load_lds(
      (const __attribute__((address_space(1))) void*)g,
      (__attribute__((address_space(3))) void*)l, 16, 0, 0);
}

// ------------- Fused LN1 + pool (both read x) -------------
// blocks [0, M1/4): LayerNorm, 4 rows each. blocks [M1/4, ...): pool.
__global__ __launch_bounds__(256) void ln1_pool(
    const float* __restrict__ X, const float* __restrict__ w,
    const float* __restrict__ b, u16* __restrict__ Y, u16* __restrict__ KV) {
  if (blockIdx.x < M1 / 4) {
    const int row = blockIdx.x * 4 + (threadIdx.x >> 6);
    const int lane = threadIdx.x & 63;
    const size_t base = (size_t)row * C_;
    float v[6];
#pragma unroll
    for (int i = 0; i < 6; ++i) v[i] = X[base + lane + 64 * i];
    float s = 0.f;
#pragma unroll
    for (int i = 0; i < 6; ++i) s += v[i];
#pragma unroll
    for (int off = 32; off > 0; off >>= 1) s += __shfl_xor(s, off);
    const float mu = s * (1.0f / C_);
    float q = 0.f;
#pragma unroll
    for (int i = 0; i < 6; ++i) { float d = v[i] - mu; q += d * d; }
#pragma unroll
    for (int off = 32; off > 0; off >>= 1) q += __shfl_xor(q, off);
    const float r = rsqrtf(q * (1.0f / C_) + 1e-6f);
#pragma unroll
    for (int i = 0; i < 6; ++i) {
      int c = lane + 64 * i;
      Y[base + c] = f2b((v[i] - mu) * r * w[c] + b[c]);
    }
  } else {
    int t = (blockIdx.x - M1 / 4) * 256 + threadIdx.x;
    if (t >= M2 * C_) return;
    int c = t % C_;
    int row = t / C_;
    int bb = row / NK;
    int rr = row - bb * NK;
    int hk = rr / 28;
    int wk = rr - hk * 28;
    const float* p = X + ((size_t)(bb * N_TOK + hk * 112 + wk * 2)) * C_ + c;
    KV[t] = f2b(0.25f * (p[0] + p[C_] + p[56 * C_] + p[57 * C_]));
  }
}

// ------------- LayerNorm bf16 -> bf16 (4 rows/block) -------------
__global__ __launch_bounds__(256) void ln2_rows(const u16* __restrict__ X,
    const float* __restrict__ w, const float* __restrict__ b, u16* __restrict__ Y) {
  const int row = blockIdx.x * 4 + (threadIdx.x >> 6);
  const int lane = threadIdx.x & 63;
  const size_t base = (size_t)row * C_;
  float v[6];
#pragma unroll
  for (int i = 0; i < 6; ++i) v[i] = b2f(X[base + lane + 64 * i]);
  float s = 0.f;
#pragma unroll
  for (int i = 0; i < 6; ++i) s += v[i];
#pragma unroll
  for (int off = 32; off > 0; off >>= 1) s += __shfl_xor(s, off);
  const float mu = s * (1.0f / C_);
  float q = 0.f;
#pragma unroll
  for (int i = 0; i < 6; ++i) { float d = v[i] - mu; q += d * d; }
#pragma unroll
  for (int off = 32; off > 0; off >>= 1) q += __shfl_xor(q, off);
  const float r = rsqrtf(q * (1.0f / C_) + 1e-6f);
#pragma unroll
  for (int i = 0; i < 6; ++i) {
    int c = lane + 64 * i;
    Y[base + c] = f2b((v[i] - mu) * r * w[c] + b[c]);
  }
}

// -------- Batched weight transpose+convert: 6 weights in one launch --------
struct TransArgs {
  const float* src[6];
  u16* dst[6];
  int K[6], N[6], tx[6], ty[6];
};
__global__ __launch_bounds__(256) void transpose_all(TransArgs a) {
  const int id = blockIdx.z;
  if ((int)blockIdx.x >= a.tx[id] || (int)blockIdx.y >= a.ty[id]) return;
  const float* W = a.src[id];
  u16* WT = a.dst[id];
  const int K = a.K[id], N = a.N[id];
  __shared__ u16 tile[64][73];
  const int k0 = blockIdx.y * 64, n0 = blockIdx.x * 64;
  for (int i = threadIdx.x; i < 64 * 64; i += 256) {
    int kk = i >> 6, nn = i & 63;
    tile[kk][nn] = f2b(W[(size_t)(k0 + kk) * N + n0 + nn]);
  }
  __syncthreads();
  for (int i = threadIdx.x; i < 64 * 64; i += 256) {
    int nn = i >> 6, kk = i & 63;
    WT[(size_t)(n0 + nn) * K + k0 + kk] = tile[kk][nn];
  }
}

// ---------------- MFMA GEMM core: C(m0..+128, n0..+128) ----------------
template<int EPI, bool RES32, bool OUT32>
__device__ __forceinline__ void gemm_core(
    const u16* __restrict__ A, const u16* __restrict__ BT,
    const float* __restrict__ bias, const void* __restrict__ resv,
    void* __restrict__ Cv, int N, int K, int m0, int n0) {
  __shared__ u16 As[128 * 64];
  __shared__ u16 Bs[128 * 64];
  const int tid  = threadIdx.x;
  const int wave = tid >> 6;
  const int lane = tid & 63;
  const int quad = lane >> 4;
  const int ll   = lane & 15;
  const int wm   = wave >> 1, wn = wave & 1;

  const int srow = wave * 32 + (lane >> 3);
  const int sgs  = lane & 7;

  f32x4 acc[4][4];
#pragma unroll
  for (int i = 0; i < 4; ++i)
#pragma unroll
    for (int j = 0; j < 4; ++j) acc[i][j] = (f32x4){0.f, 0.f, 0.f, 0.f};

  for (int kk0 = 0; kk0 < K; kk0 += 64) {
    __syncthreads();
#pragma unroll
    for (int c = 0; c < 4; ++c) {
      const int r = srow + c * 8;
      const int g = sgs ^ (r & 7);
      gload_lds16(A  + (size_t)(m0 + r) * K + kk0 + g * 8,
                  As + (size_t)(wave * 32 + c * 8) * 64);
      gload_lds16(BT + (size_t)(n0 + r) * K + kk0 + g * 8,
                  Bs + (size_t)(wave * 32 + c * 8) * 64);
    }
    __syncthreads();
#pragma unroll
    for (int ks = 0; ks < 2; ++ks) {
      const int gsw = (quad + 4 * ks) ^ (ll & 7);
      bf16x8 af[4], bfr[4];
#pragma unroll
      for (int im = 0; im < 4; ++im)
        af[im] = *(const bf16x8*)&As[(size_t)(wm * 64 + im * 16 + ll) * 64 + gsw * 8];
#pragma unroll
      for (int jn = 0; jn < 4; ++jn)
        bfr[jn] = *(const bf16x8*)&Bs[(size_t)(wn * 64 + jn * 16 + ll) * 64 + gsw * 8];
#pragma unroll
      for (int im = 0; im < 4; ++im)
#pragma unroll
        for (int jn = 0; jn < 4; ++jn)
          acc[im][jn] = __builtin_amdgcn_mfma_f32_16x16x32_bf16(
              af[im], bfr[jn], acc[im][jn], 0, 0, 0);
    }
  }

  float bb[4];
#pragma unroll
  for (int jn = 0; jn < 4; ++jn) bb[jn] = bias[n0 + wn * 64 + jn * 16 + ll];
#pragma unroll
  for (int im = 0; im < 4; ++im) {
    const int row = m0 + wm * 64 + im * 16 + quad * 4;
#pragma unroll
    for (int jn = 0; jn < 4; ++jn) {
      const int col = n0 + wn * 64 + jn * 16 + ll;
#pragma unroll
      for (int r = 0; r < 4; ++r) {
        float o = acc[im][jn][r] + bb[jn];
        if (EPI == 1) {
          o = 0.5f * o * (1.0f + erff(o * 0.70710678118654752f));
        } else if (EPI == 2) {
          size_t ri = (size_t)(row + r) * N + col;
          o += RES32 ? ((const float*)resv)[ri] : b2f(((const u16*)resv)[ri]);
        }
        if (OUT32) ((float*)Cv)[(size_t)(row + r) * N + col] = o;
        else       ((u16*)Cv)[(size_t)(row + r) * N + col] = f2b(o);
      }
    }
  }
}

template<int EPI, bool RES32, bool OUT32>
__global__ __launch_bounds__(256) void gemm_bt(
    const u16* __restrict__ A, const u16* __restrict__ BT,
    const float* __restrict__ bias, const void* __restrict__ resv,
    void* __restrict__ Cv, int N, int K) {
  gemm_core<EPI, RES32, OUT32>(A, BT, bias, resv, Cv, N, K,
                               blockIdx.y << 7, blockIdx.x << 7);
}

// Q/K/V fused: z selects {Q, K, V}; K/V blocks with y beyond M2 exit early.
struct QKVArgs {
  const u16* A[3];
  const u16* BT[3];
  const float* bias[3];
  u16* C[3];
  int M[3];
};
__global__ __launch_bounds__(256) void gemm_qkv(QKVArgs a) {
  const int z = blockIdx.z;
  const int m0 = blockIdx.y << 7;
  if (m0 >= a.M[z]) return;
  gemm_core<0, false, false>(a.A[z], a.BT[z], a.bias[z], nullptr, a.C[z],
                             C_, C_, m0, blockIdx.x << 7);
}

// ---------------- MFMA flash attention (R12: pipelined) ----------------
// Q fragments held in registers (wave-private rows); K staged via
// global_load_lds with gemm_core-style XOR swizzle, double-buffered;
// V register-staged (T14 async split), double-buffered. One barrier/iter.
// Softmax scale folded into the exp argument (Q loaded raw).
#define QS_STR 72
__global__ __launch_bounds__(512) void attn_mfma(
    const u16* __restrict__ Q, const u16* __restrict__ Kb,
    const u16* __restrict__ Vb, u16* __restrict__ O) {
  __shared__ u16 Ks[2][64 * 64];        // 16 KB  (swizzled, stride 64)
  __shared__ u16 Vt[2][48 * QS_STR];    // 13.5 KB (transposed, stride 72)
  __shared__ u16 Ps[128 * QS_STR];      // 18 KB  (wave-private rows)
  const int tid  = threadIdx.x;
  const int wave = tid >> 6;
  const int lane = tid & 63;
  const int quad = lane >> 4;
  const int ll   = lane & 15;
  const int qt   = blockIdx.x;
  const int bh   = blockIdx.y;
  const int b    = bh >> 3, h = bh & 7;
  const int q0   = qt * 128;
  const float scale = 0.14433756729740643f;   // d^-0.5, folded into exp arg

  // ---- Q fragments in registers. A-frag: lane holds A[m=ll][k=quad*8+e]. ----
  // Logical cols 48..63 are zero => garbage in K cols 48..63 contributes 0.
  bf16x8 af0, af1;
  {
    int qrow = q0 + wave * 16 + ll;
    if (qrow >= N_TOK) qrow = N_TOK - 1;       // rows masked at output
    const u16* qp = Q + ((size_t)(b * N_TOK) + qrow) * C_ + h * DH;
    af0 = *(const bf16x8*)(qp + quad * 8);                 // k = quad*8..+8  (<32)
    if (quad < 2) af1 = *(const bf16x8*)(qp + 32 + quad * 8); // k = 32..48
    else          af1 = (bf16x8){0, 0, 0, 0, 0, 0, 0, 0};    // k = 48..64 pad
  }

  // K tile prefetch: pre-swizzled global source, linear LDS dest (m173).
  const int krow = (wave << 3) + (lane >> 3);          // tile row 0..63
  const int kgrp = (lane & 7) ^ (lane >> 3);           // group g = slot ^ (row&7)
  const size_t kbase_g = (size_t)(b * NK) * C_ + h * DH + kgrp * 8;

  uint4 vreg;

  // ---- prologue: stage tile 0 ----
  {
    int kk = krow; if (kk >= NK) kk = NK - 1;
    gload_lds16(Kb + kbase_g + (size_t)kk * C_, &Ks[0][wave << 9]);
    if (wave < 6) {
      int vk = lane; if (vk >= NK) vk = NK - 1;
      vreg = *(const uint4*)(Vb + ((size_t)(b * NK) + vk) * C_ + h * DH + wave * 8);
      const u16* vp = (const u16*)&vreg;
#pragma unroll
      for (int j = 0; j < 8; ++j)
        Vt[0][(wave * 8 + j) * QS_STR + lane] = vp[j];
    }
  }
  __syncthreads();

  f32x4 Ofr[3] = {{0.f,0.f,0.f,0.f},{0.f,0.f,0.f,0.f},{0.f,0.f,0.f,0.f}};
  float lrow[4] = {0.f, 0.f, 0.f, 0.f};

  for (int t = 0; t < 13; ++t) {
    const int cur = t & 1, nxt = cur ^ 1;
    const int kbase = t * 64;

    // -- issue next-tile loads first; latency hides under QK+softmax+PV --
    if (t < 12) {
      const int knext = kbase + 64;
      int kk = knext + krow; if (kk >= NK) kk = NK - 1;
      gload_lds16(Kb + kbase_g + (size_t)kk * C_, &Ks[nxt][wave << 9]);
      if (wave < 6) {
        int vk = knext + lane; if (vk >= NK) vk = NK - 1;
        vreg = *(const uint4*)(Vb + ((size_t)(b * NK) + vk) * C_ + h * DH + wave * 8);
      }
    }

    // -- QK^T from register Q + swizzled Ks[cur] --
    f32x4 S[4];
#pragma unroll
    for (int nt = 0; nt < 4; ++nt) {
      const int rb = (nt * 16 + ll) * 64;
      bf16x8 b0 = *(const bf16x8*)&Ks[cur][rb + ((quad    ) ^ (ll & 7)) * 8];
      bf16x8 b1 = *(const bf16x8*)&Ks[cur][rb + ((quad + 4) ^ (ll & 7)) * 8];
      f32x4 acc = {0.f, 0.f, 0.f, 0.f};
      acc = __builtin_amdgcn_mfma_f32_16x16x32_bf16(af0, b0, acc, 0, 0, 0);
      acc = __builtin_amdgcn_mfma_f32_16x16x32_bf16(af1, b1, acc, 0, 0, 0);
      if (kbase + nt * 16 + ll >= NK)
        acc = (f32x4){-1e30f, -1e30f, -1e30f, -1e30f};
      S[nt] = acc;
    }

    // -- softmax numerators -> Ps (wave-private; no barrier needed) --
#pragma unroll
    for (int nt = 0; nt < 4; ++nt) {
      const int g = nt * 2 + (ll >> 3);
      const int gp = g ^ quad;
#pragma unroll
      for (int r = 0; r < 4; ++r) {
        float p = __expf(S[nt][r] * scale);
        lrow[r] += p;
        Ps[(wave * 16 + quad * 4 + r) * QS_STR + (gp << 3) + (ll & 7)] = f2b_trunc(p);
      }
    }

    // -- PV from Ps + Vt[cur] --
#pragma unroll
    for (int dt = 0; dt < 3; ++dt)
#pragma unroll
      for (int ks = 0; ks < 2; ++ks) {
        const int gp = ((ks << 2) + quad) ^ ((ll >> 2) & 3);
        bf16x8 a = *(const bf16x8*)&Ps[(wave * 16 + ll) * QS_STR + (gp << 3)];
        bf16x8 bb = *(const bf16x8*)&Vt[cur][(dt * 16 + ll) * QS_STR + ks * 32 + quad * 8];
        Ofr[dt] = __builtin_amdgcn_mfma_f32_16x16x32_bf16(a, bb, Ofr[dt], 0, 0, 0);
      }

    // -- land V regs into Vt[nxt] (auto vmcnt wait on vreg use) --
    if (t < 12 && wave < 6) {
      const u16* vp = (const u16*)&vreg;
#pragma unroll
      for (int j = 0; j < 8; ++j)
        Vt[nxt][(wave * 8 + j) * QS_STR + lane] = vp[j];
    }
    // One barrier/iter: its vmcnt(0)+lgkmcnt(0) drain also retires the
    // K global_load_lds (in flight during the whole compute phase).
    __syncthreads();
  }

#pragma unroll
  for (int msk = 1; msk < 16; msk <<= 1)
#pragma unroll
    for (int r = 0; r < 4; ++r)
      lrow[r] += __shfl_xor(lrow[r], msk);
  float inv[4];
#pragma unroll
  for (int r = 0; r < 4; ++r) inv[r] = 1.0f / lrow[r];
#pragma unroll
  for (int dt = 0; dt < 3; ++dt)
#pragma unroll
    for (int r = 0; r < 4; ++r) {
      int qrow = q0 + wave * 16 + quad * 4 + r;
      if (qrow < N_TOK)
        O[((size_t)b * N_TOK + qrow) * C_ + h * DH + dt * 16 + ll] =
            f2b(Ofr[dt][r] * inv[r]);
    }
}

// ---------------- Diagnostics ----------------
__global__ __launch_bounds__(256) void marker_fill(
    float* __restrict__ out, size_t n, float val) {
  size_t i = (size_t)blockIdx.x * 256 + threadIdx.x;
  const size_t stride = (size_t)gridDim.x * 256;
  for (; i < n; i += stride) out[i] = 0.f;
  if (blockIdx.x == 0 && threadIdx.x == 0) out[0] = val;
}

// ---------------- launch ----------------
extern "C" void kernel_launch(void* const* d_in, const int* in_sizes, int n_in,
                              void* d_out, int out_size, void* d_ws, size_t ws_size,
                              hipStream_t stream) {
  const float* x    = (const float*)d_in[0];
  const float* ln1w = (const float*)d_in[1];
  const float* ln1b = (const float*)d_in[2];
  const float* qw   = (const float*)d_in[3];
  const float* qb   = (const float*)d_in[4];
  const float* kw   = (const float*)d_in[5];
  const float* kb   = (const float*)d_in[6];
  const float* vw   = (const float*)d_in[7];
  const float* vb   = (const float*)d_in[8];
  const float* pw   = (const float*)d_in[9];
  const float* pb   = (const float*)d_in[10];
  const float* ln2w = (const float*)d_in[11];
  const float* ln2b = (const float*)d_in[12];
  const float* fc1w = (const float*)d_in[13];
  const float* fc1b = (const float*)d_in[14];
  const float* fc2w = (const float*)d_in[15];
  const float* fc2b = (const float*)d_in[16];

  const size_t BUF = (size_t)M1 * C_;
  float* outf = (float*)d_out;

  {
    static const int exp_sizes[19] = {
      M1 * C_, C_, C_, C_ * C_, C_, C_ * C_, C_, C_ * C_, C_, C_ * C_, C_,
      C_, C_, C_ * HID, HID, HID * C_, C_, 1, 1};
    int bad = -1;
    if (n_in != 19) bad = 99;
    else {
      for (int i = 0; i < 19; ++i)
        if (in_sizes[i] != exp_sizes[i]) { bad = i; break; }
    }
    if (bad >= 0) {
      marker_fill<<<1024, 256, 0, stream>>>(outf, BUF, 10000.0f + (float)bad);
      return;
    }
  }
  const size_t need_min  = 4096 + 3 * BUF * sizeof(u16);                     // 57.8 MB
  const size_t need_full = 4096 + (3 * BUF + (size_t)M1 * HID) * sizeof(u16); // 96.4 MB
  if (ws_size < need_min) {
    marker_fill<<<1024, 256, 0, stream>>>(outf, BUF, 30000.0f + (float)(ws_size >> 20));
    return;
  }
  const bool full_mlp = (ws_size >= need_full);

  u16* T0 = (u16*)((char*)d_ws + 4096);
  u16* T1 = T0 + BUF;
  u16* U  = T1 + BUF;
  u16* P  = U;
  u16* KB = U + (size_t)M2 * C_;
  u16* VB = U + (size_t)2 * M2 * C_;
  u16* HBq = U;                              // quarter-HB fallback overlay
  u16* HBfull = U + BUF;                     // full-M HB (only if full_mlp)
  u16* WTb = U + BUF - (size_t)(4 * C_ * C_ + 2 * C_ * HID);
  u16* wtq = WTb;
  u16* wtk = wtq + C_ * C_;
  u16* wtv = wtk + C_ * C_;
  u16* wtp = wtv + C_ * C_;
  u16* wtf1 = wtp + C_ * C_;
  u16* wtf2 = wtf1 + (size_t)C_ * HID;

  // 0. All six weight transposes in one launch.
  {
    TransArgs ta;
    ta.src[0] = qw;   ta.dst[0] = wtq;  ta.K[0] = C_;  ta.N[0] = C_;  ta.tx[0] = 6;  ta.ty[0] = 6;
    ta.src[1] = kw;   ta.dst[1] = wtk;  ta.K[1] = C_;  ta.N[1] = C_;  ta.tx[1] = 6;  ta.ty[1] = 6;
    ta.src[2] = vw;   ta.dst[2] = wtv;  ta.K[2] = C_;  ta.N[2] = C_;  ta.tx[2] = 6;  ta.ty[2] = 6;
    ta.src[3] = pw;   ta.dst[3] = wtp;  ta.K[3] = C_;  ta.N[3] = C_;  ta.tx[3] = 6;  ta.ty[3] = 6;
    ta.src[4] = fc1w; ta.dst[4] = wtf1; ta.K[4] = C_;  ta.N[4] = HID; ta.tx[4] = 12; ta.ty[4] = 6;
    ta.src[5] = fc2w; ta.dst[5] = wtf2; ta.K[5] = HID; ta.N[5] = C_;  ta.tx[5] = 6;  ta.ty[5] = 12;
    transpose_all<<<dim3(12, 12, 6), 256, 0, stream>>>(ta);
  }

  // 1. Fused LN1 + pool.
  ln1_pool<<<M1 / 4 + (M2 * C_) / 256, 256, 0, stream>>>(x, ln1w, ln1b, T0, P);

  // 2. Q/K/V projections in one launch.
  {
    QKVArgs qa;
    qa.A[0] = T0; qa.BT[0] = wtq; qa.bias[0] = qb; qa.C[0] = T1; qa.M[0] = M1;
    qa.A[1] = P;  qa.BT[1] = wtk; qa.bias[1] = kb; qa.C[1] = KB; qa.M[1] = M2;
    qa.A[2] = P;  qa.BT[2] = wtv; qa.bias[2] = vb; qa.C[2] = VB; qa.M[2] = M2;
    gemm_qkv<<<dim3(3, 196, 3), 256, 0, stream>>>(qa);
  }

  // 3. MFMA flash attention -> T0
  attn_mfma<<<dim3(25, 64), 512, 0, stream>>>(T1, KB, VB, T0);

  // 4. x1 = x(f32) + T0 @ pw + pb -> T1 (bf16)
  gemm_bt<2, true, false><<<dim3(3, 196), 256, 0, stream>>>(
      T0, wtp, pb, x, T1, C_, C_);

  // 5. LN2(T1) -> T0
  ln2_rows<<<M1 / 4, 256, 0, stream>>>(T1, ln2w, ln2b, T0);

  // 6/7. MLP.
  if (full_mlp) {
    gemm_bt<1, false, false><<<dim3(6, 196), 256, 0, stream>>>(
        T0, wtf1, fc1b, nullptr, HBfull, HID, C_);
    gemm_bt<2, false, true><<<dim3(3, 196), 256, 0, stream>>>(
        HBfull, wtf2, fc2b, T1, outf, C_, HID);
  } else {
    for (int qtr = 0; qtr < 4; ++qtr) {
      const size_t ro = (size_t)qtr * M1Q;
      gemm_bt<1, false, false><<<dim3(6, 49), 256, 0, stream>>>(
          T0 + ro * C_, wtf1, fc1b, nullptr, HBq, HID, C_);
      gemm_bt<2, false, true><<<dim3(3, 49), 256, 0, stream>>>(
          HBq, wtf2, fc2b, T1 + ro * C_, outf + ro * C_, C_, HID);
    }
  }
}